// Round 4
// baseline (66.276 us; speedup 1.0000x reference)
//
#include <hip/hip_runtime.h>
#include <math.h>

// Problem constants
constexpr int IMG     = 384;
constexpr int NPIX    = IMG * IMG;        // 147456
constexpr int TM1     = 10;               // T-1
constexpr int NIMG    = 80;               // B * (T-1)
constexpr int THREADS = 256;
constexpr int GPT     = 4;                // quad-groups per thread (16 px/thread)
constexpr int GPB     = THREADS * GPT;    // 1024 groups per block
constexpr int NGRP    = NPIX / 4;         // 36864 group slots (last = leftovers)
constexpr int NBX     = NGRP / GPB;       // 36 (exact)
constexpr long long NMASK = (long long)NIMG * NPIX;  // 11,796,480

typedef float v4f __attribute__((ext_vector_type(4)));

// Output layout: [0..6] = 7 scalar costs, then mask_car, mask_side, mask_light

// ---------------------------------------------------------------------------
// Kernel A: pure mask streamer. Compute 3 masks, nt-store them. Nothing else.
// ---------------------------------------------------------------------------
__global__ __launch_bounds__(THREADS) void cost_masks(
    const float* __restrict__ loc,    // (8,11,2)
    const float* __restrict__ yaw,    // (8,11,1)
    const float* __restrict__ speed,  // (8,11,1)
    float* __restrict__ out)
{
    const int img = blockIdx.y;          // 0..79
    const int b   = img / TM1;
    const int t   = img - b * TM1;       // bev time index t+1
    const int tid = threadIdx.x;

    // ---- per-image scalars ----
    const float yaw0 = yaw[b * 11];
    const float c0 = cosf(yaw0), s0 = sinf(yaw0);
    const float rx = loc[(b * 11 + t + 1) * 2 + 0] - loc[b * 22 + 0];
    const float ry = loc[(b * 11 + t + 1) * 2 + 1] - loc[b * 22 + 1];
    const float x0 =  c0 * rx + s0 * ry;
    const float y0 = -s0 * rx + c0 * ry;
    const float yw = yaw[b * 11 + t + 1] - yaw0;
    const float c = cosf(yw), s = sinf(yw);
    const float sp  = speed[b * 11 + t + 1];
    const float dy  = 1.5f * (fmaxf(10.0f, sp) + 4.9f) + 1.0f;
    const float dyl = sp * 0.5f + 14.7f;
    const float ox  = 12.0f * c + 3.25f * s;   // light-frame offsets
    const float oy  = 12.0f * s - 3.25f * c;

    float* ocar   = out + 7 + (size_t)img * NPIX;
    float* oside  = ocar + NMASK;
    float* olight = ocar + 2 * NMASK;

    const int g0 = blockIdx.x * GPB + tid;
    #pragma unroll
    for (int it = 0; it < GPT; ++it) {
        const int g = g0 + it * THREADS;
        if (g != NGRP - 1) {
            const int pb = 4 * g + 1;        // pixels pb..pb+3, 16B-aligned in out
            float mc[4], ms[4], ml[4];
            #pragma unroll
            for (int k = 0; k < 4; ++k) {
                const int p = pb + k;
                const int i = p / IMG;
                const int j = p - i * IMG;
                const float X = (float)j * 0.2f - 38.4f;
                const float Y = (float)i * 0.2f - 38.4f;
                const float relx = X - x0, rely = Y - y0;
                const float ax = c * relx + s * rely;
                const float ay = c * rely - s * relx;
                const float axl = ax - ox, ayl = ay + oy;
                mc[k] = (fabsf(ax)  <= 5.05f  && ay >= 0.f && ay <= dy)   ? 1.f : 0.f;
                ms[k] = (fabsf(ax)  <= 1.155f && fabsf(ay) <= 2.695f)     ? 1.f : 0.f;
                ml[k] = (fabsf(axl) <= 3.1f   && ayl >= 0.f && ayl <= dyl)? 1.f : 0.f;
            }
            v4f vc = {mc[0], mc[1], mc[2], mc[3]};
            v4f vs = {ms[0], ms[1], ms[2], ms[3]};
            v4f vl = {ml[0], ml[1], ml[2], ml[3]};
            __builtin_nontemporal_store(vc, (v4f*)(ocar + pb));
            __builtin_nontemporal_store(vs, (v4f*)(oside + pb));
            __builtin_nontemporal_store(vl, (v4f*)(olight + pb));
        } else {
            // leftover pixels {0, NPIX-3, NPIX-2, NPIX-1} for this image
            const int pp[4] = {0, NPIX - 3, NPIX - 2, NPIX - 1};
            for (int k = 0; k < 4; ++k) {
                const int p = pp[k];
                const int i = p / IMG;
                const int j = p - i * IMG;
                const float X = (float)j * 0.2f - 38.4f;
                const float Y = (float)i * 0.2f - 38.4f;
                const float relx = X - x0, rely = Y - y0;
                const float ax = c * relx + s * rely;
                const float ay = c * rely - s * relx;
                const float axl = ax - ox, ayl = ay + oy;
                ocar[p]   = (fabsf(ax)  <= 5.05f  && ay >= 0.f && ay <= dy)    ? 1.f : 0.f;
                oside[p]  = (fabsf(ax)  <= 1.155f && fabsf(ay) <= 2.695f)      ? 1.f : 0.f;
                olight[p] = (fabsf(axl) <= 3.1f   && ayl >= 0.f && ayl <= dyl) ? 1.f : 0.f;
            }
        }
    }
}

// ---------------------------------------------------------------------------
// Kernel B: cost sums. Walk only the analytic bounding box of each rotated
// region, re-evaluate the exact same predicates, gated bev reads, block
// reduce, one atomic batch per block.
// grid = (NIMG, 3 regions, 4 stripes)
// ---------------------------------------------------------------------------
__global__ __launch_bounds__(THREADS) void cost_sums(
    const float* __restrict__ loc,
    const float* __restrict__ yaw,
    const float* __restrict__ speed,
    const float* __restrict__ bev,
    float* __restrict__ out)
{
    const int img = blockIdx.x;          // 0..79
    const int reg = blockIdx.y;          // 0=car, 1=side, 2=light
    const int z   = blockIdx.z;          // stripe 0..3
    const int b   = img / TM1;
    const int t   = img - b * TM1;
    const int tid = threadIdx.x;

    const float yaw0 = yaw[b * 11];
    const float c0 = cosf(yaw0), s0 = sinf(yaw0);
    const float rx = loc[(b * 11 + t + 1) * 2 + 0] - loc[b * 22 + 0];
    const float ry = loc[(b * 11 + t + 1) * 2 + 1] - loc[b * 22 + 1];
    const float x0 =  c0 * rx + s0 * ry;
    const float y0 = -s0 * rx + c0 * ry;
    const float yw = yaw[b * 11 + t + 1] - yaw0;
    const float c = cosf(yw), s = sinf(yw);
    const float sp  = speed[b * 11 + t + 1];
    const float dy  = 1.5f * (fmaxf(10.0f, sp) + 4.9f) + 1.0f;
    const float dyl = sp * 0.5f + 14.7f;
    const float ox  = 12.0f * c + 3.25f * s;
    const float oy  = 12.0f * s - 3.25f * c;

    const float* bp = bev + (size_t)((b * 11 + t + 1) * 8) * NPIX;

    // region rect in aligned (ax, ay) coords
    float u0, u1, v0, v1;
    if (reg == 0)      { u0 = -5.05f;      u1 = 5.05f;      v0 = 0.f;      v1 = dy; }
    else if (reg == 1) { u0 = -1.155f;     u1 = 1.155f;     v0 = -2.695f;  v1 = 2.695f; }
    else               { u0 = ox - 3.1f;   u1 = ox + 3.1f;  v0 = -oy;      v1 = dyl - oy; }

    // bbox in (X, Y) via inverse rotation of the 4 corners
    float Xmn = 1e30f, Xmx = -1e30f, Ymn = 1e30f, Ymx = -1e30f;
    #pragma unroll
    for (int cu = 0; cu < 2; ++cu)
        #pragma unroll
        for (int cv = 0; cv < 2; ++cv) {
            const float u = cu ? u1 : u0, v = cv ? v1 : v0;
            const float X = x0 + c * u - s * v;
            const float Y = y0 + s * u + c * v;
            Xmn = fminf(Xmn, X); Xmx = fmaxf(Xmx, X);
            Ymn = fminf(Ymn, Y); Ymx = fmaxf(Ymx, Y);
        }
    const int j0 = max(0, (int)floorf((Xmn + 38.4f) * 5.f) - 1);
    const int j1 = min(IMG - 1, (int)ceilf((Xmx + 38.4f) * 5.f) + 1);
    const int i0 = max(0, (int)floorf((Ymn + 38.4f) * 5.f) - 1);
    const int i1 = min(IMG - 1, (int)ceilf((Ymx + 38.4f) * 5.f) + 1);

    float a0 = 0.f, a1 = 0.f, a2 = 0.f;   // up to 3 channel sums for this region

    if (j1 >= j0 && i1 >= i0) {
        const int w = j1 - j0 + 1;
        const int n = w * (i1 - i0 + 1);
        for (int idx = tid + z * THREADS; idx < n; idx += 4 * THREADS) {
            const int ii = idx / w;
            const int jj = j0 + (idx - ii * w);
            const int i  = i0 + ii;
            const float X = (float)jj * 0.2f - 38.4f;
            const float Y = (float)i  * 0.2f - 38.4f;
            const float relx = X - x0, rely = Y - y0;
            const float ax = c * relx + s * rely;
            const float ay = c * rely - s * relx;
            const int p = i * IMG + jj;
            if (reg == 0) {
                if (fabsf(ax) <= 5.05f && ay >= 0.f && ay <= dy) {
                    a0 += (bp[2 * NPIX + p] > 0.5f) ? 1.f : 0.f;   // vehicle
                    a1 += (bp[6 * NPIX + p] > 0.5f) ? 1.f : 0.f;   // pedestrian
                }
            } else if (reg == 1) {
                if (fabsf(ax) <= 1.155f && fabsf(ay) <= 2.695f) {
                    a0 += (bp[1 * NPIX + p] > 0.5f) ? 1.f : 0.f;   // lane
                    a1 += (bp[7 * NPIX + p] > 0.5f) ? 1.f : 0.f;   // offroad
                }
            } else {
                const float axl = ax - ox, ayl = ay + oy;
                if (fabsf(axl) <= 3.1f && ayl >= 0.f && ayl <= dyl) {
                    a0 += (bp[3 * NPIX + p] > 0.5f) ? 1.f : 0.f;   // green
                    a1 += (bp[4 * NPIX + p] > 0.5f) ? 1.f : 0.f;   // yellow
                    a2 += (bp[5 * NPIX + p] > 0.5f) ? 1.f : 0.f;   // red
                }
            }
        }
    }

    // block reduction of 3 accumulators
    float acc[3] = {a0, a1, a2};
    #pragma unroll
    for (int k = 0; k < 3; ++k) {
        #pragma unroll
        for (int off = 32; off > 0; off >>= 1)
            acc[k] += __shfl_down(acc[k], off, 64);
    }
    __shared__ float red[4][3];
    const int wid = tid >> 6, lane = tid & 63;
    if (lane == 0) {
        #pragma unroll
        for (int k = 0; k < 3; ++k) red[wid][k] = acc[k];
    }
    __syncthreads();
    if (tid < 3) {
        const float v = red[0][tid] + red[1][tid] + red[2][tid] + red[3][tid];
        if (v != 0.0f) {
            float decay = 1.0f;
            for (int q = 0; q < t; ++q) decay *= 0.97f;
            // out slot mapping: lane=0, vehicle=1, green=2, yellow=3, red=4, ped=5, offroad=6
            int slot;
            if (reg == 0)      slot = (tid == 0) ? 1 : 5;      // vehicle, pedestrian
            else if (reg == 1) slot = (tid == 0) ? 0 : 6;      // lane, offroad
            else               slot = 2 + tid;                 // green, yellow, red
            if (reg == 2 || tid < 2)
                atomicAdd(&out[slot], v * decay);
        }
    }
}

extern "C" void kernel_launch(void* const* d_in, const int* in_sizes, int n_in,
                              void* d_out, int out_size, void* d_ws, size_t ws_size,
                              hipStream_t stream) {
    const float* loc   = (const float*)d_in[0];
    const float* yaw   = (const float*)d_in[1];
    const float* speed = (const float*)d_in[2];
    const float* bev   = (const float*)d_in[3];
    float* out = (float*)d_out;

    // zero the 7 scalar cost slots (atomics accumulate into them)
    (void)hipMemsetAsync(d_out, 0, 7 * sizeof(float), stream);

    dim3 gridA(NBX, NIMG);
    cost_masks<<<gridA, THREADS, 0, stream>>>(loc, yaw, speed, out);

    dim3 gridB(NIMG, 3, 4);
    cost_sums<<<gridB, THREADS, 0, stream>>>(loc, yaw, speed, bev, out);
}

// Round 5
// 39.567 us; speedup vs baseline: 1.6751x; 1.6751x over previous
//
#include <hip/hip_runtime.h>
#include <math.h>

// Problem constants
constexpr int IMG     = 384;
constexpr int NPIX    = IMG * IMG;        // 147456
constexpr int TM1     = 10;               // T-1
constexpr int NIMG    = 80;               // B * (T-1)
constexpr int THREADS = 256;
constexpr int GPT     = 4;                // quad-groups per thread (16 px/thread)
constexpr int GPB     = THREADS * GPT;    // 1024 groups per block
constexpr int NGRP    = NPIX / 4;         // 36864 group slots (last = leftovers)
constexpr int NBX     = NGRP / GPB;       // 36 (exact)
constexpr long long NMASK = (long long)NIMG * NPIX;  // 11,796,480

typedef float v4f __attribute__((ext_vector_type(4)));

// Output layout: [0..6] = 7 scalar costs, then mask_car, mask_side, mask_light

__global__ __launch_bounds__(THREADS) void cost_main(
    const float* __restrict__ loc,    // (8,11,2)
    const float* __restrict__ yaw,    // (8,11,1)
    const float* __restrict__ speed,  // (8,11,1)
    const float* __restrict__ bev,    // (8,11,8,384,384)
    float* __restrict__ out)
{
    const int img = blockIdx.y;          // 0..79
    const int b   = img / TM1;
    const int t   = img - b * TM1;       // bev time index t+1
    const int tid = threadIdx.x;

    // ---- per-image scalars ----
    const float yaw0 = yaw[b * 11];
    const float c0 = cosf(yaw0), s0 = sinf(yaw0);
    const float rx = loc[(b * 11 + t + 1) * 2 + 0] - loc[b * 22 + 0];
    const float ry = loc[(b * 11 + t + 1) * 2 + 1] - loc[b * 22 + 1];
    const float x0 =  c0 * rx + s0 * ry;
    const float y0 = -s0 * rx + c0 * ry;
    const float yw = yaw[b * 11 + t + 1] - yaw0;
    const float c = cosf(yw), s = sinf(yw);
    const float sp  = speed[b * 11 + t + 1];
    const float dy  = 1.5f * (fmaxf(10.0f, sp) + 4.9f) + 1.0f;
    const float dyl = sp * 0.5f + 14.7f;
    const float ox  = 12.0f * c + 3.25f * s;   // light-frame offsets
    const float oy  = 12.0f * s - 3.25f * c;

    const float* bp = bev + (size_t)((b * 11 + t + 1) * 8) * NPIX;
    float* ocar   = out + 7 + (size_t)img * NPIX;
    float* oside  = ocar + NMASK;
    float* olight = ocar + 2 * NMASK;

    float aL = 0.f, aV = 0.f, aG = 0.f, aY = 0.f, aR = 0.f, aP = 0.f, aO = 0.f;

    const int g0 = blockIdx.x * GPB + tid;
    #pragma unroll
    for (int it = 0; it < GPT; ++it) {
        const int g = g0 + it * THREADS;
        if (g != NGRP - 1) {
            const int pb = 4 * g + 1;        // pixels pb..pb+3, 16B-aligned in out
            float mc[4], ms[4], ml[4];
            #pragma unroll
            for (int k = 0; k < 4; ++k) {
                const int p = pb + k;
                const int i = p / IMG;
                const int j = p - i * IMG;
                const float X = (float)j * 0.2f - 38.4f;
                const float Y = (float)i * 0.2f - 38.4f;
                const float relx = X - x0, rely = Y - y0;
                const float ax = c * relx + s * rely;
                const float ay = c * rely - s * relx;
                const float axl = ax - ox, ayl = ay + oy;
                mc[k] = (fabsf(ax)  <= 5.05f  && ay >= 0.f && ay <= dy)   ? 1.f : 0.f;
                ms[k] = (fabsf(ax)  <= 1.155f && fabsf(ay) <= 2.695f)     ? 1.f : 0.f;
                ml[k] = (fabsf(axl) <= 3.1f   && ayl >= 0.f && ayl <= dyl)? 1.f : 0.f;
            }
            v4f vc = {mc[0], mc[1], mc[2], mc[3]};
            v4f vs = {ms[0], ms[1], ms[2], ms[3]};
            v4f vl = {ml[0], ml[1], ml[2], ml[3]};
            *(v4f*)(ocar + pb)   = vc;
            *(v4f*)(oside + pb)  = vs;
            *(v4f*)(olight + pb) = vl;

            if (ms[0] + ms[1] + ms[2] + ms[3] > 0.f) {
                #pragma unroll
                for (int k = 0; k < 4; ++k) {
                    aL += ms[k] * ((bp[1 * NPIX + pb + k] > 0.5f) ? 1.f : 0.f);
                    aO += ms[k] * ((bp[7 * NPIX + pb + k] > 0.5f) ? 1.f : 0.f);
                }
            }
            if (mc[0] + mc[1] + mc[2] + mc[3] > 0.f) {
                #pragma unroll
                for (int k = 0; k < 4; ++k) {
                    aV += mc[k] * ((bp[2 * NPIX + pb + k] > 0.5f) ? 1.f : 0.f);
                    aP += mc[k] * ((bp[6 * NPIX + pb + k] > 0.5f) ? 1.f : 0.f);
                }
            }
            if (ml[0] + ml[1] + ml[2] + ml[3] > 0.f) {
                #pragma unroll
                for (int k = 0; k < 4; ++k) {
                    aG += ml[k] * ((bp[3 * NPIX + pb + k] > 0.5f) ? 1.f : 0.f);
                    aY += ml[k] * ((bp[4 * NPIX + pb + k] > 0.5f) ? 1.f : 0.f);
                    aR += ml[k] * ((bp[5 * NPIX + pb + k] > 0.5f) ? 1.f : 0.f);
                }
            }
        } else {
            // leftover pixels {0, NPIX-3, NPIX-2, NPIX-1} for this image
            const int pp[4] = {0, NPIX - 3, NPIX - 2, NPIX - 1};
            for (int k = 0; k < 4; ++k) {
                const int p = pp[k];
                const int i = p / IMG;
                const int j = p - i * IMG;
                const float X = (float)j * 0.2f - 38.4f;
                const float Y = (float)i * 0.2f - 38.4f;
                const float relx = X - x0, rely = Y - y0;
                const float ax = c * relx + s * rely;
                const float ay = c * rely - s * relx;
                const float axl = ax - ox, ayl = ay + oy;
                const float mc = (fabsf(ax)  <= 5.05f  && ay >= 0.f && ay <= dy)    ? 1.f : 0.f;
                const float msd= (fabsf(ax)  <= 1.155f && fabsf(ay) <= 2.695f)      ? 1.f : 0.f;
                const float ml = (fabsf(axl) <= 3.1f   && ayl >= 0.f && ayl <= dyl) ? 1.f : 0.f;
                ocar[p] = mc; oside[p] = msd; olight[p] = ml;
                if (msd > 0.f) {
                    aL += (bp[1 * NPIX + p] > 0.5f) ? 1.f : 0.f;
                    aO += (bp[7 * NPIX + p] > 0.5f) ? 1.f : 0.f;
                }
                if (mc > 0.f) {
                    aV += (bp[2 * NPIX + p] > 0.5f) ? 1.f : 0.f;
                    aP += (bp[6 * NPIX + p] > 0.5f) ? 1.f : 0.f;
                }
                if (ml > 0.f) {
                    aG += (bp[3 * NPIX + p] > 0.5f) ? 1.f : 0.f;
                    aY += (bp[4 * NPIX + p] > 0.5f) ? 1.f : 0.f;
                    aR += (bp[5 * NPIX + p] > 0.5f) ? 1.f : 0.f;
                }
            }
        }
    }

    // ---- block reduction of the 7 accumulators ----
    float acc[7] = {aL, aV, aG, aY, aR, aP, aO};
    #pragma unroll
    for (int k = 0; k < 7; ++k) {
        #pragma unroll
        for (int off = 32; off > 0; off >>= 1)
            acc[k] += __shfl_down(acc[k], off, 64);
    }

    __shared__ float red[4][7];
    const int wid = tid >> 6, lane = tid & 63;
    if (lane == 0) {
        #pragma unroll
        for (int k = 0; k < 7; ++k) red[wid][k] = acc[k];
    }
    __syncthreads();
    if (tid < 7) {
        const float v = red[0][tid] + red[1][tid] + red[2][tid] + red[3][tid];
        if (v != 0.0f) {
            float decay = 1.0f;
            for (int q = 0; q < t; ++q) decay *= 0.97f;
            atomicAdd(&out[tid], v * decay);
        }
    }
}

extern "C" void kernel_launch(void* const* d_in, const int* in_sizes, int n_in,
                              void* d_out, int out_size, void* d_ws, size_t ws_size,
                              hipStream_t stream) {
    const float* loc   = (const float*)d_in[0];
    const float* yaw   = (const float*)d_in[1];
    const float* speed = (const float*)d_in[2];
    const float* bev   = (const float*)d_in[3];
    float* out = (float*)d_out;

    // zero the 7 scalar cost slots (atomics accumulate into them)
    (void)hipMemsetAsync(d_out, 0, 7 * sizeof(float), stream);

    dim3 grid(NBX, NIMG);
    cost_main<<<grid, THREADS, 0, stream>>>(loc, yaw, speed, bev, out);
}

// Round 6
// 38.329 us; speedup vs baseline: 1.7291x; 1.0323x over previous
//
#include <hip/hip_runtime.h>
#include <math.h>

// Problem constants
constexpr int IMG     = 384;
constexpr int NPIX    = IMG * IMG;        // 147456
constexpr int TM1     = 10;               // T-1
constexpr int NIMG    = 80;               // B * (T-1)
constexpr int THREADS = 256;
constexpr int GPT     = 4;                // quad-groups per thread (16 px/thread)
constexpr int GPB     = THREADS * GPT;    // 1024 groups per block
constexpr int NGRP    = NPIX / 4;         // 36864 group slots (last = leftovers)
constexpr int NBX     = NGRP / GPB;       // 36 streamer blocks per image
constexpr int NSUM    = 12;               // 3 regions x 4 stripes per image
constexpr long long NMASK = (long long)NIMG * NPIX;  // 11,796,480

typedef float v4f __attribute__((ext_vector_type(4)));

// Output layout: [0..6] = 7 scalar costs, then mask_car, mask_side, mask_light

__global__ __launch_bounds__(THREADS) void cost_main(
    const float* __restrict__ loc,    // (8,11,2)
    const float* __restrict__ yaw,    // (8,11,1)
    const float* __restrict__ speed,  // (8,11,1)
    const float* __restrict__ bev,    // (8,11,8,384,384)
    float* __restrict__ out)
{
    const int img = blockIdx.y;          // 0..79
    const int b   = img / TM1;
    const int t   = img - b * TM1;       // bev time index t+1
    const int tid = threadIdx.x;

    // ---- per-image scalars (both paths) ----
    const float yaw0 = yaw[b * 11];
    const float c0 = cosf(yaw0), s0 = sinf(yaw0);
    const float rx = loc[(b * 11 + t + 1) * 2 + 0] - loc[b * 22 + 0];
    const float ry = loc[(b * 11 + t + 1) * 2 + 1] - loc[b * 22 + 1];
    const float x0 =  c0 * rx + s0 * ry;
    const float y0 = -s0 * rx + c0 * ry;
    const float yw = yaw[b * 11 + t + 1] - yaw0;
    const float c = cosf(yw), s = sinf(yw);
    const float sp  = speed[b * 11 + t + 1];
    const float dy  = 1.5f * (fmaxf(10.0f, sp) + 4.9f) + 1.0f;
    const float dyl = sp * 0.5f + 14.7f;
    const float ox  = 12.0f * c + 3.25f * s;   // light-frame offsets
    const float oy  = 12.0f * s - 3.25f * c;

    if (blockIdx.x < NBX) {
        // ================= streamer path: pure compute + stores =============
        float* ocar   = out + 7 + (size_t)img * NPIX;
        float* oside  = ocar + NMASK;
        float* olight = ocar + 2 * NMASK;

        const int g0 = blockIdx.x * GPB + tid;
        #pragma unroll
        for (int it = 0; it < GPT; ++it) {
            const int g = g0 + it * THREADS;
            if (g != NGRP - 1) {
                const int pb = 4 * g + 1;    // pixels pb..pb+3, 16B-aligned
                float mc[4], ms[4], ml[4];
                #pragma unroll
                for (int k = 0; k < 4; ++k) {
                    const int p = pb + k;
                    const int i = p / IMG;
                    const int j = p - i * IMG;
                    const float X = (float)j * 0.2f - 38.4f;
                    const float Y = (float)i * 0.2f - 38.4f;
                    const float relx = X - x0, rely = Y - y0;
                    const float ax = c * relx + s * rely;
                    const float ay = c * rely - s * relx;
                    const float axl = ax - ox, ayl = ay + oy;
                    mc[k] = (fabsf(ax)  <= 5.05f  && ay >= 0.f && ay <= dy)   ? 1.f : 0.f;
                    ms[k] = (fabsf(ax)  <= 1.155f && fabsf(ay) <= 2.695f)     ? 1.f : 0.f;
                    ml[k] = (fabsf(axl) <= 3.1f   && ayl >= 0.f && ayl <= dyl)? 1.f : 0.f;
                }
                v4f vc = {mc[0], mc[1], mc[2], mc[3]};
                v4f vs = {ms[0], ms[1], ms[2], ms[3]};
                v4f vl = {ml[0], ml[1], ml[2], ml[3]};
                *(v4f*)(ocar + pb)   = vc;
                *(v4f*)(oside + pb)  = vs;
                *(v4f*)(olight + pb) = vl;
            } else {
                // leftover pixels {0, NPIX-3, NPIX-2, NPIX-1}
                const int pp[4] = {0, NPIX - 3, NPIX - 2, NPIX - 1};
                for (int k = 0; k < 4; ++k) {
                    const int p = pp[k];
                    const int i = p / IMG;
                    const int j = p - i * IMG;
                    const float X = (float)j * 0.2f - 38.4f;
                    const float Y = (float)i * 0.2f - 38.4f;
                    const float relx = X - x0, rely = Y - y0;
                    const float ax = c * relx + s * rely;
                    const float ay = c * rely - s * relx;
                    const float axl = ax - ox, ayl = ay + oy;
                    ocar[p]   = (fabsf(ax)  <= 5.05f  && ay >= 0.f && ay <= dy)    ? 1.f : 0.f;
                    oside[p]  = (fabsf(ax)  <= 1.155f && fabsf(ay) <= 2.695f)      ? 1.f : 0.f;
                    olight[p] = (fabsf(axl) <= 3.1f   && ayl >= 0.f && ayl <= dyl) ? 1.f : 0.f;
                }
            }
        }
        return;
    }

    // ================= sum path: bbox walk + gated loads ====================
    const int q   = blockIdx.x - NBX;    // 0..11
    const int reg = q >> 2;              // 0=car, 1=side, 2=light
    const int z   = q & 3;               // stripe 0..3

    const float* bp = bev + (size_t)((b * 11 + t + 1) * 8) * NPIX;

    // region rect in aligned (ax, ay) coords
    float u0, u1, v0, v1;
    if (reg == 0)      { u0 = -5.05f;      u1 = 5.05f;      v0 = 0.f;      v1 = dy; }
    else if (reg == 1) { u0 = -1.155f;     u1 = 1.155f;     v0 = -2.695f;  v1 = 2.695f; }
    else               { u0 = ox - 3.1f;   u1 = ox + 3.1f;  v0 = -oy;      v1 = dyl - oy; }

    // bbox in (X, Y) via inverse rotation of the 4 corners
    float Xmn = 1e30f, Xmx = -1e30f, Ymn = 1e30f, Ymx = -1e30f;
    #pragma unroll
    for (int cu = 0; cu < 2; ++cu)
        #pragma unroll
        for (int cv = 0; cv < 2; ++cv) {
            const float u = cu ? u1 : u0, v = cv ? v1 : v0;
            const float X = x0 + c * u - s * v;
            const float Y = y0 + s * u + c * v;
            Xmn = fminf(Xmn, X); Xmx = fmaxf(Xmx, X);
            Ymn = fminf(Ymn, Y); Ymx = fmaxf(Ymx, Y);
        }
    const int j0 = max(0, (int)floorf((Xmn + 38.4f) * 5.f) - 1);
    const int j1 = min(IMG - 1, (int)ceilf((Xmx + 38.4f) * 5.f) + 1);
    const int i0 = max(0, (int)floorf((Ymn + 38.4f) * 5.f) - 1);
    const int i1 = min(IMG - 1, (int)ceilf((Ymx + 38.4f) * 5.f) + 1);

    float a0 = 0.f, a1 = 0.f, a2 = 0.f;

    if (j1 >= j0 && i1 >= i0) {
        const int w = j1 - j0 + 1;
        const int n = w * (i1 - i0 + 1);
        for (int idx = tid + z * THREADS; idx < n; idx += 4 * THREADS) {
            const int ii = idx / w;
            const int jj = j0 + (idx - ii * w);
            const int i  = i0 + ii;
            const float X = (float)jj * 0.2f - 38.4f;
            const float Y = (float)i  * 0.2f - 38.4f;
            const float relx = X - x0, rely = Y - y0;
            const float ax = c * relx + s * rely;
            const float ay = c * rely - s * relx;
            const int p = i * IMG + jj;
            if (reg == 0) {
                if (fabsf(ax) <= 5.05f && ay >= 0.f && ay <= dy) {
                    a0 += (bp[2 * NPIX + p] > 0.5f) ? 1.f : 0.f;   // vehicle
                    a1 += (bp[6 * NPIX + p] > 0.5f) ? 1.f : 0.f;   // pedestrian
                }
            } else if (reg == 1) {
                if (fabsf(ax) <= 1.155f && fabsf(ay) <= 2.695f) {
                    a0 += (bp[1 * NPIX + p] > 0.5f) ? 1.f : 0.f;   // lane
                    a1 += (bp[7 * NPIX + p] > 0.5f) ? 1.f : 0.f;   // offroad
                }
            } else {
                const float axl = ax - ox, ayl = ay + oy;
                if (fabsf(axl) <= 3.1f && ayl >= 0.f && ayl <= dyl) {
                    a0 += (bp[3 * NPIX + p] > 0.5f) ? 1.f : 0.f;   // green
                    a1 += (bp[4 * NPIX + p] > 0.5f) ? 1.f : 0.f;   // yellow
                    a2 += (bp[5 * NPIX + p] > 0.5f) ? 1.f : 0.f;   // red
                }
            }
        }
    }

    // block reduction of 3 accumulators
    float acc[3] = {a0, a1, a2};
    #pragma unroll
    for (int k = 0; k < 3; ++k) {
        #pragma unroll
        for (int off = 32; off > 0; off >>= 1)
            acc[k] += __shfl_down(acc[k], off, 64);
    }
    __shared__ float red[4][3];
    const int wid = tid >> 6, lane = tid & 63;
    if (lane == 0) {
        #pragma unroll
        for (int k = 0; k < 3; ++k) red[wid][k] = acc[k];
    }
    __syncthreads();
    if (tid < 3) {
        const float v = red[0][tid] + red[1][tid] + red[2][tid] + red[3][tid];
        if (v != 0.0f) {
            float decay = 1.0f;
            for (int qd = 0; qd < t; ++qd) decay *= 0.97f;
            // slots: lane=0, vehicle=1, green=2, yellow=3, red=4, ped=5, offroad=6
            int slot;
            if (reg == 0)      slot = (tid == 0) ? 1 : 5;      // vehicle, pedestrian
            else if (reg == 1) slot = (tid == 0) ? 0 : 6;      // lane, offroad
            else               slot = 2 + tid;                 // green, yellow, red
            if (reg == 2 || tid < 2)
                atomicAdd(&out[slot], v * decay);
        }
    }
}

extern "C" void kernel_launch(void* const* d_in, const int* in_sizes, int n_in,
                              void* d_out, int out_size, void* d_ws, size_t ws_size,
                              hipStream_t stream) {
    const float* loc   = (const float*)d_in[0];
    const float* yaw   = (const float*)d_in[1];
    const float* speed = (const float*)d_in[2];
    const float* bev   = (const float*)d_in[3];
    float* out = (float*)d_out;

    // zero the 7 scalar cost slots (atomics accumulate into them)
    (void)hipMemsetAsync(d_out, 0, 7 * sizeof(float), stream);

    dim3 grid(NBX + NSUM, NIMG);
    cost_main<<<grid, THREADS, 0, stream>>>(loc, yaw, speed, bev, out);
}